// Round 1
// baseline (3587.252 us; speedup 1.0000x reference)
//
#include <hip/hip_runtime.h>
#include <math.h>

namespace {
constexpr int LSEQ = 32;
constexpr int CDIM = 64;
constexpr int HDIM = 128;
constexpr int FDIM = 32;

__device__ __forceinline__ float sigf(float x) { return 1.0f / (1.0f + expf(-x)); }
}

__global__ __launch_bounds__(256)
void sfm_lstm_kernel(const float* __restrict__ x,
                     const float* __restrict__ Q,
                     const float* __restrict__ R,
                     const float* __restrict__ Wi,   const float* __restrict__ bi,
                     const float* __restrict__ Wg,   const float* __restrict__ bg,
                     const float* __restrict__ Wste, const float* __restrict__ bste,
                     const float* __restrict__ Wfre, const float* __restrict__ bfre,
                     const float* __restrict__ Wom,  const float* __restrict__ bom,
                     const float* __restrict__ Wo,   const float* __restrict__ bo,
                     const float* __restrict__ Wa,   const float* __restrict__ ba,
                     const float* __restrict__ Wout, const float* __restrict__ bout,
                     float* __restrict__ out)
{
    const int t    = threadIdx.x;
    const int s    = blockIdx.x;
    const int hh   = t >> 1;        // pair index: output row for most phases
    const int half = t & 1;         // which half of the dot this thread sums
    const int f0   = half * (FDIM / 2);

    __shared__ float s_x[CDIM];     // xt (also first 64 of ih/oh)
    __shared__ float s_h[HDIM];     // h  (ih[64:192], oh[64:192])
    __shared__ float s_it[HDIM];
    __shared__ float s_chat[HDIM];
    __shared__ float s_fste[HDIM];
    __shared__ float s_ffre[FDIM];
    __shared__ float s_cos[FDIM];
    __shared__ float s_sin[FDIM];
    __shared__ float s_ct[HDIM];
    __shared__ float s_wa[FDIM];

    if (t < HDIM) s_h[t] = 0.0f;
    if (t < FDIM) s_wa[t] = Wa[t];
    const float ba0 = ba[0];

    // per-thread slice of the (H=128, F=32) re/im state: row hh, cols [f0, f0+16)
    float re[FDIM / 2], im[FDIM / 2];
    #pragma unroll
    for (int j = 0; j < FDIM / 2; ++j) { re[j] = 0.0f; im[j] = 0.0f; }

    // fixed per-thread gate output assignment (uniform per wave)
    const float* wA; int jA;
    if (t < HDIM) { wA = Wi; jA = t; } else { wA = Wg; jA = t - HDIM; }
    const float* wB = Wste; int jB = 0, strB = HDIM;   // defaults overwritten below
    if      (t < 128) { wB = Wste; jB = t;       strB = HDIM; }
    else if (t < 160) { wB = Wfre; jB = t - 128; strB = FDIM; }
    else if (t < 192) { wB = Wom;  jB = t - 160; strB = FDIM; }

    const float* xseq = x + (size_t)s * (LSEQ * CDIM);

    for (int ts = 0; ts < LSEQ; ++ts) {
        if (t < CDIM) s_x[t] = xseq[ts * CDIM + t];
        __syncthreads();

        // ---- mogrify: x, h, x, h, x ----
        for (int m = 0; m < 5; ++m) {
            if ((m & 1) == 0) {
                // xt = 2*sig(h @ Q) * xt   (64 outputs, 2 threads each)
                if (t < 2 * CDIM) {
                    const int c = hh;                          // 0..63
                    const float* q  = Q + (half * (HDIM / 2)) * CDIM + c;
                    const float* hv = s_h + half * (HDIM / 2);
                    float sum = 0.0f;
                    #pragma unroll 8
                    for (int k = 0; k < HDIM / 2; ++k) sum += hv[k] * q[k * CDIM];
                    sum += __shfl_xor(sum, 1);
                    if (half == 0) s_x[c] = 2.0f * sigf(sum) * s_x[c];
                }
            } else {
                // h = 2*sig(xt @ R) * h    (128 outputs, 2 threads each)
                const float* r  = R + (half * (CDIM / 2)) * HDIM + hh;
                const float* xv = s_x + half * (CDIM / 2);
                float sum = 0.0f;
                #pragma unroll 8
                for (int k = 0; k < CDIM / 2; ++k) sum += xv[k] * r[k * HDIM];
                sum += __shfl_xor(sum, 1);
                if (half == 0) s_h[hh] = 2.0f * sigf(sum) * s_h[hh];
            }
            __syncthreads();
        }

        // ---- gates: ih(192) @ [Wi|Wg | Wste|Wfre|Wom] ----
        {
            float sA = 0.0f, sB = 0.0f;
            if (t < 192) {
                #pragma unroll 4
                for (int k = 0; k < CDIM; ++k) {
                    const float v = s_x[k];
                    sA += v * wA[k * HDIM + jA];
                    sB += v * wB[k * strB + jB];
                }
                #pragma unroll 4
                for (int k = 0; k < HDIM; ++k) {
                    const float v = s_h[k];
                    sA += v * wA[(CDIM + k) * HDIM + jA];
                    sB += v * wB[(CDIM + k) * strB + jB];
                }
            } else {
                #pragma unroll 4
                for (int k = 0; k < CDIM; ++k) sA += s_x[k] * wA[k * HDIM + jA];
                #pragma unroll 4
                for (int k = 0; k < HDIM; ++k) sA += s_h[k] * wA[(CDIM + k) * HDIM + jA];
            }
            if (t < HDIM) s_it[t] = sigf(sA + bi[t]);
            else          s_chat[t - HDIM] = sigf(sA + bg[t - HDIM]);
            if      (t < 128) s_fste[t] = sigf(sB + bste[t]);
            else if (t < 160) s_ffre[t - 128] = sigf(sB + bfre[t - 128]);
            else if (t < 192) {
                const float om = 6.28318530717958647692f * sigf(sB + bom[t - 160]);
                s_cos[t - 160] = cosf(om);
                s_sin[t - 160] = sinf(om);
            }
        }
        __syncthreads();

        // ---- complex state update + amplitude @ Wa ----
        {
            const float fh  = s_fste[hh];
            const float ich = s_it[hh] * s_chat[hh];
            float acc = 0.0f;
            #pragma unroll
            for (int j = 0; j < FDIM / 2; ++j) {
                const int f = f0 + j;
                const float ft = fh * s_ffre[f];
                re[j] = ft * re[j] + ich * s_cos[f];
                im[j] = ft * im[j] + ich * s_sin[f];
                acc += sqrtf(re[j] * re[j] + im[j] * im[j]) * s_wa[f];
            }
            acc += __shfl_xor(acc, 1);
            if (half == 0) s_ct[hh] = tanhf(acc + ba0);
        }
        __syncthreads();

        // ---- o_t = sig(oh(320) @ Wo), h = o_t * tanh(c_t) ----
        {
            const int j = hh;                               // 0..127
            float sum = 0.0f;
            if (half == 0) {                                // oh[0:160)
                #pragma unroll 4
                for (int k = 0; k < CDIM; ++k) sum += s_x[k] * Wo[k * HDIM + j];
                #pragma unroll 4
                for (int k = 0; k < 96; ++k)   sum += s_h[k] * Wo[(CDIM + k) * HDIM + j];
            } else {                                        // oh[160:320)
                #pragma unroll 4
                for (int k = 96; k < HDIM; ++k) sum += s_h[k]  * Wo[(CDIM + k) * HDIM + j];
                #pragma unroll 4
                for (int k = 0; k < HDIM; ++k)  sum += s_ct[k] * Wo[(192 + k) * HDIM + j];
            }
            sum += __shfl_xor(sum, 1);
            __syncthreads();            // all reads of s_x/s_h/s_ct complete before h write
            if (half == 0) {
                const float o = sigf(sum + bo[j]);
                s_h[j] = o * tanhf(s_ct[j]);
            }
        }
        // top-of-loop barrier orders the s_h write against next step's reads
    }

    __syncthreads();
    if (t < 64) {
        float p = s_h[t] * Wout[t] + s_h[t + 64] * Wout[t + 64];
        #pragma unroll
        for (int off = 32; off > 0; off >>= 1) p += __shfl_xor(p, off);
        if (t == 0) out[s] = p + bout[0];
    }
}

extern "C" void kernel_launch(void* const* d_in, const int* in_sizes, int n_in,
                              void* d_out, int out_size, void* d_ws, size_t ws_size,
                              hipStream_t stream) {
    const float* x    = (const float*)d_in[0];
    const float* Q    = (const float*)d_in[1];
    const float* R    = (const float*)d_in[2];
    const float* Wi   = (const float*)d_in[3];
    const float* bi   = (const float*)d_in[4];
    const float* Wg   = (const float*)d_in[5];
    const float* bg   = (const float*)d_in[6];
    const float* Wste = (const float*)d_in[7];
    const float* bste = (const float*)d_in[8];
    const float* Wfre = (const float*)d_in[9];
    const float* bfre = (const float*)d_in[10];
    const float* Wom  = (const float*)d_in[11];
    const float* bom  = (const float*)d_in[12];
    const float* Wo   = (const float*)d_in[13];
    const float* bo   = (const float*)d_in[14];
    const float* Wa   = (const float*)d_in[15];
    const float* ba   = (const float*)d_in[16];
    const float* Wout = (const float*)d_in[17];
    const float* bout = (const float*)d_in[18];
    float* out = (float*)d_out;

    sfm_lstm_kernel<<<dim3(1024), dim3(256), 0, stream>>>(
        x, Q, R, Wi, bi, Wg, bg, Wste, bste, Wfre, bfre, Wom, bom,
        Wo, bo, Wa, ba, Wout, bout, out);
}

// Round 2
// 757.411 us; speedup vs baseline: 4.7362x; 4.7362x over previous
//
#include <hip/hip_runtime.h>
#include <math.h>

namespace {
constexpr int LSEQ = 32;
constexpr int CDIM = 64;
constexpr int HDIM = 128;
constexpr int FDIM = 32;
constexpr float TWO_PI = 6.28318530717958647692f;

__device__ __forceinline__ float sigf(float x) { return 1.0f / (1.0f + expf(-x)); }
}

// S=4 sequences per block, 256 blocks (1 per CU), 256 threads.
// State layout in LDS is transposed: s*[dim][4] so one b128 broadcast read
// yields all 4 sequences' values for a given k.
__global__ __launch_bounds__(256, 1)
void sfm_lstm_s4(const float* __restrict__ x,
                 const float* __restrict__ Q, const float* __restrict__ R,
                 const float* __restrict__ Wi, const float* __restrict__ bi,
                 const float* __restrict__ Wg, const float* __restrict__ bg,
                 const float* __restrict__ Wste, const float* __restrict__ bste,
                 const float* __restrict__ Wfre, const float* __restrict__ bfre,
                 const float* __restrict__ Wom, const float* __restrict__ bom,
                 const float* __restrict__ Wo, const float* __restrict__ bo,
                 const float* __restrict__ Wa, const float* __restrict__ ba,
                 const float* __restrict__ Wout, const float* __restrict__ bout,
                 float* __restrict__ out)
{
    const int t = threadIdx.x;
    const int blk = blockIdx.x;

    __shared__ float sQ[HDIM * CDIM];                 // 32 KB  Q[k][c]
    __shared__ float sR[CDIM * HDIM];                 // 32 KB  R[k][j]
    __shared__ __align__(16) float sx[CDIM][4];
    __shared__ __align__(16) float sh[HDIM][4];
    __shared__ __align__(16) float sct[HDIM][4];
    __shared__ __align__(16) float sit[HDIM][4];
    __shared__ __align__(16) float schat[HDIM][4];
    __shared__ __align__(16) float sfste[HDIM][4];
    __shared__ __align__(16) float sffre[FDIM][4];
    __shared__ __align__(16) float scos[FDIM][4];
    __shared__ __align__(16) float ssin[FDIM][4];
    __shared__ __align__(16) float spart[2048];       // 8 KB partial sums
    __shared__ float swa[FDIM];

    #pragma unroll
    for (int i = 0; i < 32; ++i) sQ[t + 256 * i] = Q[t + 256 * i];
    #pragma unroll
    for (int i = 0; i < 32; ++i) sR[t + 256 * i] = R[t + 256 * i];
    if (t < FDIM) swa[t] = Wa[t];
    {
        const int r = t & 127, s0 = t >> 7;
        sh[r][s0] = 0.0f; sh[r][s0 + 2] = 0.0f;
    }

    // per-thread complex state: rows r7 = t&127, seqs sA = t>>7 and sA+2
    float re[2][FDIM], im[2][FDIM];
    #pragma unroll
    for (int f = 0; f < FDIM; ++f) { re[0][f] = 0.f; re[1][f] = 0.f; im[0][f] = 0.f; im[1][f] = 0.f; }

    // gate phase: thread owns a column PAIR of the concatenated gate weights
    const float* wG = nullptr; const float* bGp = nullptr;
    int strG = 0, j0 = 0, reg = -1;
    if      (t < 64)  { wG = Wi;   bGp = bi;   strG = HDIM; j0 = 2 * t;         reg = 0; }
    else if (t < 128) { wG = Wg;   bGp = bg;   strG = HDIM; j0 = 2 * (t - 64);  reg = 1; }
    else if (t < 192) { wG = Wste; bGp = bste; strG = HDIM; j0 = 2 * (t - 128); reg = 2; }
    else if (t < 208) { wG = Wfre; bGp = bfre; strG = FDIM; j0 = 2 * (t - 192); reg = 3; }
    else if (t < 224) { wG = Wom;  bGp = bom;  strG = FDIM; j0 = 2 * (t - 208); reg = 4; }
    const float gb0 = (reg >= 0) ? bGp[j0] : 0.0f;
    const float gb1 = (reg >= 0) ? bGp[j0 + 1] : 0.0f;
    const float* wGp = (reg >= 0) ? (wG + j0) : Wi;

    const float ba0 = ba[0];
    const float bor = bo[t & 127];
    const float* xp = x + (size_t)((blk * 4 + (t >> 6)) * LSEQ) * CDIM + (t & 63);

    const int r7 = t & 127, sA = t >> 7, sB = sA + 2;
    const int pp = t & 63, kq = t >> 6;
    const float* woP = Wo + 2 * pp;

    for (int ts = 0; ts < LSEQ; ++ts) {
        // ---- P0: load x tile ----
        sx[t & 63][t >> 6] = xp[ts * CDIM];
        __syncthreads();

        // ---- mogrify x,h,x,h,x ----
        #pragma unroll
        for (int m = 0; m < 5; ++m) {
            if ((m & 1) == 0) {
                // xt = 2*sig(h @ Q) * xt : 64 cols x 4 seqs, k split 4 ways
                const int c = t & 63, kk0 = (t >> 6) * 32;
                float a0 = 0.f, a1 = 0.f, a2 = 0.f, a3 = 0.f;
                #pragma unroll 8
                for (int kk = 0; kk < 32; ++kk) {
                    const int k = kk0 + kk;
                    const float qv = sQ[k * CDIM + c];
                    const float4 h4 = *(const float4*)&sh[k][0];
                    a0 += qv * h4.x; a1 += qv * h4.y; a2 += qv * h4.z; a3 += qv * h4.w;
                }
                *(float4*)&spart[(t >> 6) * 256 + c * 4] = make_float4(a0, a1, a2, a3);
                __syncthreads();
                {
                    const int c2 = t >> 2, s2 = t & 3, o = c2 * 4 + s2;
                    const float v = spart[o] + spart[256 + o] + spart[512 + o] + spart[768 + o];
                    sx[c2][s2] = 2.0f * sigf(v) * sx[c2][s2];
                }
                __syncthreads();
            } else {
                // h = 2*sig(x @ R) * h : 128 cols x 4 seqs, k split 2 ways
                const int j = t & 127, kk0 = (t >> 7) * 32;
                float a0 = 0.f, a1 = 0.f, a2 = 0.f, a3 = 0.f;
                #pragma unroll 8
                for (int kk = 0; kk < 32; ++kk) {
                    const int k = kk0 + kk;
                    const float rv = sR[k * HDIM + j];
                    const float4 x4 = *(const float4*)&sx[k][0];
                    a0 += rv * x4.x; a1 += rv * x4.y; a2 += rv * x4.z; a3 += rv * x4.w;
                }
                *(float4*)&spart[(t >> 7) * 512 + j * 4] = make_float4(a0, a1, a2, a3);
                __syncthreads();
                #pragma unroll
                for (int i = 0; i < 2; ++i) {
                    const int idx = t + 256 * i;
                    const int jj = idx & 127, s2 = idx >> 7, o = jj * 4 + s2;
                    const float v = spart[o] + spart[512 + o];
                    sh[jj][s2] = 2.0f * sigf(v) * sh[jj][s2];
                }
                __syncthreads();
            }
        }

        // ---- gates: ih(192) @ [Wi|Wg|Wste|Wfre|Wom], 2 cols x 4 seqs per thread ----
        if (reg >= 0) {
            float g00 = 0.f, g01 = 0.f, g02 = 0.f, g03 = 0.f;
            float g10 = 0.f, g11 = 0.f, g12 = 0.f, g13 = 0.f;
            #pragma unroll 4
            for (int k = 0; k < CDIM; ++k) {
                const float2 w2 = *(const float2*)(wGp + k * strG);
                const float4 i4 = *(const float4*)&sx[k][0];
                g00 += w2.x * i4.x; g01 += w2.x * i4.y; g02 += w2.x * i4.z; g03 += w2.x * i4.w;
                g10 += w2.y * i4.x; g11 += w2.y * i4.y; g12 += w2.y * i4.z; g13 += w2.y * i4.w;
            }
            #pragma unroll 4
            for (int k = 0; k < HDIM; ++k) {
                const float2 w2 = *(const float2*)(wGp + (CDIM + k) * strG);
                const float4 i4 = *(const float4*)&sh[k][0];
                g00 += w2.x * i4.x; g01 += w2.x * i4.y; g02 += w2.x * i4.z; g03 += w2.x * i4.w;
                g10 += w2.y * i4.x; g11 += w2.y * i4.y; g12 += w2.y * i4.z; g13 += w2.y * i4.w;
            }
            if (reg == 4) {
                const float o00 = TWO_PI * sigf(g00 + gb0), o01 = TWO_PI * sigf(g01 + gb0);
                const float o02 = TWO_PI * sigf(g02 + gb0), o03 = TWO_PI * sigf(g03 + gb0);
                const float o10 = TWO_PI * sigf(g10 + gb1), o11 = TWO_PI * sigf(g11 + gb1);
                const float o12 = TWO_PI * sigf(g12 + gb1), o13 = TWO_PI * sigf(g13 + gb1);
                scos[j0][0] = cosf(o00); ssin[j0][0] = sinf(o00);
                scos[j0][1] = cosf(o01); ssin[j0][1] = sinf(o01);
                scos[j0][2] = cosf(o02); ssin[j0][2] = sinf(o02);
                scos[j0][3] = cosf(o03); ssin[j0][3] = sinf(o03);
                scos[j0 + 1][0] = cosf(o10); ssin[j0 + 1][0] = sinf(o10);
                scos[j0 + 1][1] = cosf(o11); ssin[j0 + 1][1] = sinf(o11);
                scos[j0 + 1][2] = cosf(o12); ssin[j0 + 1][2] = sinf(o12);
                scos[j0 + 1][3] = cosf(o13); ssin[j0 + 1][3] = sinf(o13);
            } else {
                float* d = (reg == 0) ? &sit[0][0] : (reg == 1) ? &schat[0][0]
                         : (reg == 2) ? &sfste[0][0] : &sffre[0][0];
                *(float4*)&d[j0 * 4] =
                    make_float4(sigf(g00 + gb0), sigf(g01 + gb0), sigf(g02 + gb0), sigf(g03 + gb0));
                *(float4*)&d[(j0 + 1) * 4] =
                    make_float4(sigf(g10 + gb1), sigf(g11 + gb1), sigf(g12 + gb1), sigf(g13 + gb1));
            }
        }
        __syncthreads();

        // ---- complex state update + amplitude @ Wa -> c_t ----
        {
            const float4 it4 = *(const float4*)&sit[r7][0];
            const float4 ch4 = *(const float4*)&schat[r7][0];
            const float4 fs4 = *(const float4*)&sfste[r7][0];
            const float icA = sA ? it4.y * ch4.y : it4.x * ch4.x;
            const float icB = sA ? it4.w * ch4.w : it4.z * ch4.z;
            const float fsA = sA ? fs4.y : fs4.x;
            const float fsB = sA ? fs4.w : fs4.z;
            float accA = 0.0f, accB = 0.0f;
            #pragma unroll
            for (int f = 0; f < FDIM; ++f) {
                const float4 fr4 = *(const float4*)&sffre[f][0];
                const float4 co4 = *(const float4*)&scos[f][0];
                const float4 si4 = *(const float4*)&ssin[f][0];
                const float wv = swa[f];
                {
                    const float ft = fsA * (sA ? fr4.y : fr4.x);
                    const float cv = sA ? co4.y : co4.x;
                    const float sv = sA ? si4.y : si4.x;
                    re[0][f] = ft * re[0][f] + icA * cv;
                    im[0][f] = ft * im[0][f] + icA * sv;
                    accA += sqrtf(re[0][f] * re[0][f] + im[0][f] * im[0][f]) * wv;
                }
                {
                    const float ft = fsB * (sA ? fr4.w : fr4.z);
                    const float cv = sA ? co4.w : co4.z;
                    const float sv = sA ? si4.w : si4.z;
                    re[1][f] = ft * re[1][f] + icB * cv;
                    im[1][f] = ft * im[1][f] + icB * sv;
                    accB += sqrtf(re[1][f] * re[1][f] + im[1][f] * im[1][f]) * wv;
                }
            }
            sct[r7][sA] = tanhf(accA + ba0);
            sct[r7][sB] = tanhf(accB + ba0);
        }
        __syncthreads();

        // ---- o_t = sig(oh(320) @ Wo); h = o_t * tanh(c_t) ----
        {
            float o00 = 0.f, o01 = 0.f, o02 = 0.f, o03 = 0.f;
            float o10 = 0.f, o11 = 0.f, o12 = 0.f, o13 = 0.f;
            const int k0 = kq * 80, k1 = k0 + 80;
            int ka = k0, kb = (k1 < 64) ? k1 : 64;
            #pragma unroll 4
            for (int k = ka; k < kb; ++k) {
                const float2 w2 = *(const float2*)(woP + k * HDIM);
                const float4 i4 = *(const float4*)&sx[k][0];
                o00 += w2.x * i4.x; o01 += w2.x * i4.y; o02 += w2.x * i4.z; o03 += w2.x * i4.w;
                o10 += w2.y * i4.x; o11 += w2.y * i4.y; o12 += w2.y * i4.z; o13 += w2.y * i4.w;
            }
            ka = (k0 > 64) ? k0 : 64; kb = (k1 < 192) ? k1 : 192;
            #pragma unroll 4
            for (int k = ka; k < kb; ++k) {
                const float2 w2 = *(const float2*)(woP + k * HDIM);
                const float4 i4 = *(const float4*)&sh[k - 64][0];
                o00 += w2.x * i4.x; o01 += w2.x * i4.y; o02 += w2.x * i4.z; o03 += w2.x * i4.w;
                o10 += w2.y * i4.x; o11 += w2.y * i4.y; o12 += w2.y * i4.z; o13 += w2.y * i4.w;
            }
            ka = (k0 > 192) ? k0 : 192;
            #pragma unroll 4
            for (int k = ka; k < k1; ++k) {
                const float2 w2 = *(const float2*)(woP + k * HDIM);
                const float4 i4 = *(const float4*)&sct[k - 192][0];
                o00 += w2.x * i4.x; o01 += w2.x * i4.y; o02 += w2.x * i4.z; o03 += w2.x * i4.w;
                o10 += w2.y * i4.x; o11 += w2.y * i4.y; o12 += w2.y * i4.z; o13 += w2.y * i4.w;
            }
            *(float4*)&spart[kq * 512 + pp * 8]     = make_float4(o00, o01, o02, o03);
            *(float4*)&spart[kq * 512 + pp * 8 + 4] = make_float4(o10, o11, o12, o13);
        }
        __syncthreads();
        {
            const int base = (r7 >> 1) * 8 + (r7 & 1) * 4;
            const float vA = spart[base + sA] + spart[512 + base + sA]
                           + spart[1024 + base + sA] + spart[1536 + base + sA];
            const float vB = spart[base + sB] + spart[512 + base + sB]
                           + spart[1024 + base + sB] + spart[1536 + base + sB];
            const float oA = sigf(vA + bor);
            const float oB = sigf(vB + bor);
            sh[r7][sA] = oA * tanhf(sct[r7][sA]);
            sh[r7][sB] = oB * tanhf(sct[r7][sB]);
        }
        __syncthreads();
    }

    // ---- out = h_last @ Wout + bout, one wave per sequence ----
    {
        const int w = t >> 6, l = t & 63;
        float p = sh[l][w] * Wout[l] + sh[l + 64][w] * Wout[l + 64];
        #pragma unroll
        for (int off = 32; off > 0; off >>= 1) p += __shfl_xor(p, off);
        if (l == 0) out[blk * 4 + w] = p + bout[0];
    }
}

extern "C" void kernel_launch(void* const* d_in, const int* in_sizes, int n_in,
                              void* d_out, int out_size, void* d_ws, size_t ws_size,
                              hipStream_t stream) {
    const float* x    = (const float*)d_in[0];
    const float* Q    = (const float*)d_in[1];
    const float* R    = (const float*)d_in[2];
    const float* Wi   = (const float*)d_in[3];
    const float* bi   = (const float*)d_in[4];
    const float* Wg   = (const float*)d_in[5];
    const float* bg   = (const float*)d_in[6];
    const float* Wste = (const float*)d_in[7];
    const float* bste = (const float*)d_in[8];
    const float* Wfre = (const float*)d_in[9];
    const float* bfre = (const float*)d_in[10];
    const float* Wom  = (const float*)d_in[11];
    const float* bom  = (const float*)d_in[12];
    const float* Wo   = (const float*)d_in[13];
    const float* bo   = (const float*)d_in[14];
    const float* Wa   = (const float*)d_in[15];
    const float* ba   = (const float*)d_in[16];
    const float* Wout = (const float*)d_in[17];
    const float* bout = (const float*)d_in[18];
    float* out = (float*)d_out;

    sfm_lstm_s4<<<dim3(256), dim3(256), 0, stream>>>(
        x, Q, R, Wi, bi, Wg, bg, Wste, bste, Wfre, bfre, Wom, bom,
        Wo, bo, Wa, ba, Wout, bout, out);
}

// Round 3
// 434.544 us; speedup vs baseline: 8.2552x; 1.7430x over previous
//
#include <hip/hip_runtime.h>
#include <math.h>

namespace {
constexpr int LSEQ = 32;
constexpr int CDIM = 64;
constexpr int HDIM = 128;
constexpr int FDIM = 32;
constexpr float TWO_PI = 6.28318530717958647692f;

__device__ __forceinline__ float sigf(float x) { return 1.0f / (1.0f + __expf(-x)); }
// tanh(x) = 1 - 2/(e^{2x}+1); exact at both saturation ends, ~ulp error mid-range
__device__ __forceinline__ float tanh_fast(float x) { return 1.0f - 2.0f / (__expf(2.0f * x) + 1.0f); }
}

// S=4 sequences/block, 256 blocks (1/CU), 512 threads (8 waves -> 2 waves/SIMD).
__global__ __launch_bounds__(512, 1)
void sfm_lstm_s4w8(const float* __restrict__ x,
                   const float* __restrict__ Q, const float* __restrict__ R,
                   const float* __restrict__ Wi, const float* __restrict__ bi,
                   const float* __restrict__ Wg, const float* __restrict__ bg,
                   const float* __restrict__ Wste, const float* __restrict__ bste,
                   const float* __restrict__ Wfre, const float* __restrict__ bfre,
                   const float* __restrict__ Wom, const float* __restrict__ bom,
                   const float* __restrict__ Wo, const float* __restrict__ bo,
                   const float* __restrict__ Wa, const float* __restrict__ ba,
                   const float* __restrict__ Wout, const float* __restrict__ bout,
                   float* __restrict__ out)
{
    const int t = threadIdx.x;
    const int blk = blockIdx.x;

    __shared__ float sQ[HDIM * CDIM];                  // Q[k][c]
    __shared__ float sR[CDIM * HDIM];                  // R[k][j]
    __shared__ __align__(16) float sx[CDIM][4];        // [dim][seq] for b128 broadcast
    __shared__ __align__(16) float sh[HDIM][4];
    __shared__ __align__(16) float sct[HDIM][4];
    __shared__ float sit[4][HDIM];                     // seq-major: conflict-free scalar access
    __shared__ float schat[4][HDIM];
    __shared__ float sfste[4][HDIM];
    __shared__ float sffre[4][FDIM];
    __shared__ float scosv[4][FDIM];
    __shared__ float ssinv[4][FDIM];
    __shared__ __align__(16) float spart[2048];
    __shared__ float swa[FDIM];

    #pragma unroll
    for (int i = 0; i < 16; ++i) sQ[t + 512 * i] = Q[t + 512 * i];
    #pragma unroll
    for (int i = 0; i < 16; ++i) sR[t + 512 * i] = R[t + 512 * i];
    if (t < FDIM) swa[t] = Wa[t];
    sh[t >> 2][t & 3] = 0.0f;

    // per-thread complex state: one (row r7, seq sA); sA is wave-uniform
    const int r7 = t & 127;
    const int sA = t >> 7;
    float re[FDIM], im[FDIM];
    #pragma unroll
    for (int f = 0; f < FDIM; ++f) { re[f] = 0.0f; im[f] = 0.0f; }

    // gate role: one output column of the concatenated gate matrices per thread
    const float* wG = nullptr; const float* bG = nullptr;
    int strG = HDIM, gcol = 0, reg = -1;
    if      (t < 128) { wG = Wi;   bG = bi;   strG = HDIM; gcol = t;       reg = 0; }
    else if (t < 256) { wG = Wg;   bG = bg;   strG = HDIM; gcol = t - 128; reg = 1; }
    else if (t < 384) { wG = Wste; bG = bste; strG = HDIM; gcol = t - 256; reg = 2; }
    else if (t < 416) { wG = Wfre; bG = bfre; strG = FDIM; gcol = t - 384; reg = 3; }
    else if (t < 448) { wG = Wom;  bG = bom;  strG = FDIM; gcol = t - 416; reg = 4; }
    const float gb = (reg >= 0) ? bG[gcol] : 0.0f;
    const float* wGp0 = (reg >= 0) ? (wG + gcol) : Wi;

    const float ba0 = ba[0];
    const float bor = bo[t >> 2];                       // out-reduce col = t>>2
    const float* xp = x + (size_t)((blk * 4 + (t >> 6)) * LSEQ) * CDIM + (t & 63);

    const int ocol = t & 127, oks = t >> 7;             // out matvec: col + k-slice (wave-uniform)
    const float* woP = Wo + ocol;

    for (int ts = 0; ts < LSEQ; ++ts) {
        if (t < 256) sx[t & 63][t >> 6] = xp[ts * CDIM];
        __syncthreads();

        // ---- mogrify x,h,x,h,x ----
        #pragma unroll
        for (int m = 0; m < 5; ++m) {
            if ((m & 1) == 0) {
                // xt = 2*sig(h @ Q) * xt : 64 cols x 4 seqs, k split 8-way x 16
                const int c = t & 63, k0 = (t >> 6) * 16;
                float a0 = 0.f, a1 = 0.f, a2 = 0.f, a3 = 0.f;
                #pragma unroll
                for (int kk = 0; kk < 16; ++kk) {
                    const int k = k0 + kk;
                    const float qv = sQ[k * CDIM + c];
                    const float4 h4 = *(const float4*)&sh[k][0];
                    a0 += qv * h4.x; a1 += qv * h4.y; a2 += qv * h4.z; a3 += qv * h4.w;
                }
                *(float4*)&spart[(t >> 6) * 256 + c * 4] = make_float4(a0, a1, a2, a3);
                __syncthreads();
                if (t < 256) {
                    float v = 0.f;
                    #pragma unroll
                    for (int i = 0; i < 8; ++i) v += spart[i * 256 + t];
                    sx[t >> 2][t & 3] = 2.0f * sigf(v) * sx[t >> 2][t & 3];
                }
                __syncthreads();
            } else {
                // h = 2*sig(x @ R) * h : 128 cols x 4 seqs, k split 4-way x 16
                const int j = t & 127, k0 = (t >> 7) * 16;
                float a0 = 0.f, a1 = 0.f, a2 = 0.f, a3 = 0.f;
                #pragma unroll
                for (int kk = 0; kk < 16; ++kk) {
                    const int k = k0 + kk;
                    const float rv = sR[k * HDIM + j];
                    const float4 x4 = *(const float4*)&sx[k][0];
                    a0 += rv * x4.x; a1 += rv * x4.y; a2 += rv * x4.z; a3 += rv * x4.w;
                }
                *(float4*)&spart[(t >> 7) * 512 + j * 4] = make_float4(a0, a1, a2, a3);
                __syncthreads();
                {
                    const float v = spart[t] + spart[512 + t] + spart[1024 + t] + spart[1536 + t];
                    sh[t >> 2][t & 3] = 2.0f * sigf(v) * sh[t >> 2][t & 3];
                }
                __syncthreads();
            }
        }

        // ---- gates: ih(192) @ [Wi|Wg|Wste|Wfre|Wom], 1 col x 4 seqs per thread ----
        if (reg >= 0) {
            float g0 = 0.f, g1 = 0.f, g2 = 0.f, g3 = 0.f;
            const float* wp = wGp0;
            #pragma unroll 8
            for (int k = 0; k < CDIM; ++k) {
                const float w = *wp; wp += strG;
                const float4 i4 = *(const float4*)&sx[k][0];
                g0 += w * i4.x; g1 += w * i4.y; g2 += w * i4.z; g3 += w * i4.w;
            }
            #pragma unroll 8
            for (int k = 0; k < HDIM; ++k) {
                const float w = *wp; wp += strG;
                const float4 i4 = *(const float4*)&sh[k][0];
                g0 += w * i4.x; g1 += w * i4.y; g2 += w * i4.z; g3 += w * i4.w;
            }
            g0 += gb; g1 += gb; g2 += gb; g3 += gb;
            if (reg == 4) {
                const float o0 = TWO_PI * sigf(g0), o1 = TWO_PI * sigf(g1);
                const float o2 = TWO_PI * sigf(g2), o3 = TWO_PI * sigf(g3);
                scosv[0][gcol] = __cosf(o0); ssinv[0][gcol] = __sinf(o0);
                scosv[1][gcol] = __cosf(o1); ssinv[1][gcol] = __sinf(o1);
                scosv[2][gcol] = __cosf(o2); ssinv[2][gcol] = __sinf(o2);
                scosv[3][gcol] = __cosf(o3); ssinv[3][gcol] = __sinf(o3);
            } else {
                float* d = (reg == 0) ? &sit[0][0] : (reg == 1) ? &schat[0][0]
                         : (reg == 2) ? &sfste[0][0] : &sffre[0][0];
                const int dstr = (reg == 3) ? FDIM : HDIM;
                d[0 * dstr + gcol] = sigf(g0);
                d[1 * dstr + gcol] = sigf(g1);
                d[2 * dstr + gcol] = sigf(g2);
                d[3 * dstr + gcol] = sigf(g3);
            }
        }
        __syncthreads();

        // ---- complex state update + amplitude @ Wa -> c_t : one (row,seq)/thread ----
        {
            const float ic = sit[sA][r7] * schat[sA][r7];
            const float fs = sfste[sA][r7];
            float acc = 0.f;
            #pragma unroll
            for (int f = 0; f < FDIM; ++f) {
                const float ft = fs * sffre[sA][f];
                const float cv = scosv[sA][f], sv = ssinv[sA][f];
                re[f] = ft * re[f] + ic * cv;
                im[f] = ft * im[f] + ic * sv;
                acc += sqrtf(re[f] * re[f] + im[f] * im[f]) * swa[f];
            }
            sct[r7][sA] = tanh_fast(acc + ba0);
        }
        __syncthreads();

        // ---- o_t = sig(oh(320) @ Wo): 128 cols x 4 k-slices (wave-uniform) ----
        {
            float o0 = 0.f, o1 = 0.f, o2 = 0.f, o3 = 0.f;
            if (oks == 0) {
                #pragma unroll 8
                for (int k = 0; k < 64; ++k) {
                    const float w = woP[k * HDIM];
                    const float4 i4 = *(const float4*)&sx[k][0];
                    o0 += w * i4.x; o1 += w * i4.y; o2 += w * i4.z; o3 += w * i4.w;
                }
                #pragma unroll 8
                for (int k = 0; k < 16; ++k) {
                    const float w = woP[(64 + k) * HDIM];
                    const float4 i4 = *(const float4*)&sh[k][0];
                    o0 += w * i4.x; o1 += w * i4.y; o2 += w * i4.z; o3 += w * i4.w;
                }
            } else if (oks == 1) {
                #pragma unroll 8
                for (int k = 0; k < 80; ++k) {
                    const float w = woP[(80 + k) * HDIM];
                    const float4 i4 = *(const float4*)&sh[16 + k][0];
                    o0 += w * i4.x; o1 += w * i4.y; o2 += w * i4.z; o3 += w * i4.w;
                }
            } else if (oks == 2) {
                #pragma unroll 8
                for (int k = 0; k < 32; ++k) {
                    const float w = woP[(160 + k) * HDIM];
                    const float4 i4 = *(const float4*)&sh[96 + k][0];
                    o0 += w * i4.x; o1 += w * i4.y; o2 += w * i4.z; o3 += w * i4.w;
                }
                #pragma unroll 8
                for (int k = 0; k < 48; ++k) {
                    const float w = woP[(192 + k) * HDIM];
                    const float4 i4 = *(const float4*)&sct[k][0];
                    o0 += w * i4.x; o1 += w * i4.y; o2 += w * i4.z; o3 += w * i4.w;
                }
            } else {
                #pragma unroll 8
                for (int k = 0; k < 80; ++k) {
                    const float w = woP[(240 + k) * HDIM];
                    const float4 i4 = *(const float4*)&sct[48 + k][0];
                    o0 += w * i4.x; o1 += w * i4.y; o2 += w * i4.z; o3 += w * i4.w;
                }
            }
            *(float4*)&spart[oks * 512 + ocol * 4] = make_float4(o0, o1, o2, o3);
        }
        __syncthreads();
        {
            const float v = spart[t] + spart[512 + t] + spart[1024 + t] + spart[1536 + t];
            const float o = sigf(v + bor);
            sh[t >> 2][t & 3] = o * tanh_fast(sct[t >> 2][t & 3]);
        }
        __syncthreads();
    }

    // ---- out = h_last @ Wout + bout, one wave-group per sequence ----
    if (t < 256) {
        const int w = t >> 6, l = t & 63;
        float p = sh[l][w] * Wout[l] + sh[l + 64][w] * Wout[l + 64];
        #pragma unroll
        for (int off = 32; off > 0; off >>= 1) p += __shfl_xor(p, off);
        if (l == 0) out[blk * 4 + w] = p + bout[0];
    }
}

extern "C" void kernel_launch(void* const* d_in, const int* in_sizes, int n_in,
                              void* d_out, int out_size, void* d_ws, size_t ws_size,
                              hipStream_t stream) {
    const float* x    = (const float*)d_in[0];
    const float* Q    = (const float*)d_in[1];
    const float* R    = (const float*)d_in[2];
    const float* Wi   = (const float*)d_in[3];
    const float* bi   = (const float*)d_in[4];
    const float* Wg   = (const float*)d_in[5];
    const float* bg   = (const float*)d_in[6];
    const float* Wste = (const float*)d_in[7];
    const float* bste = (const float*)d_in[8];
    const float* Wfre = (const float*)d_in[9];
    const float* bfre = (const float*)d_in[10];
    const float* Wom  = (const float*)d_in[11];
    const float* bom  = (const float*)d_in[12];
    const float* Wo   = (const float*)d_in[13];
    const float* bo   = (const float*)d_in[14];
    const float* Wa   = (const float*)d_in[15];
    const float* ba   = (const float*)d_in[16];
    const float* Wout = (const float*)d_in[17];
    const float* bout = (const float*)d_in[18];
    float* out = (float*)d_out;

    sfm_lstm_s4w8<<<dim3(256), dim3(512), 0, stream>>>(
        x, Q, R, Wi, bi, Wg, bg, Wste, bste, Wfre, bfre, Wom, bom,
        Wo, bo, Wa, ba, Wout, bout, out);
}